// Round 1
// baseline (2898.831 us; speedup 1.0000x reference)
//
#include <hip/hip_runtime.h>
#include <hip/hip_bf16.h>
#include <math.h>

#define SLOPE 0.2f

static inline int imin(int a, int b) { return a < b ? a : b; }

// order-preserving float->uint map for atomicMax-based float max
__device__ __forceinline__ unsigned fmap(float f) {
    unsigned u = __float_as_uint(f);
    return (u & 0x80000000u) ? ~u : (u | 0x80000000u);
}
__device__ __forceinline__ float funmap(unsigned u) {
    unsigned v = (u & 0x80000000u) ? (u & 0x7FFFFFFFu) : ~u;
    return __uint_as_float(v);
}

// h = x @ W  (x:[N,128], W:[128,HC]), plus a_s[n,h]=sum_c h*att_s, a_d likewise.
// HC=128 (H=2,C=64) for layer 1, HC=64 (H=1) for layer 2.
template<int HC>
__global__ __launch_bounds__(256)
void gemm_att(const float* __restrict__ x, const float* __restrict__ W,
              const float* __restrict__ att_s, const float* __restrict__ att_d,
              float* __restrict__ h, float* __restrict__ a_s, float* __restrict__ a_d,
              int N) {
    constexpr int RG = 256 / HC;   // row groups per block
    constexpr int R = 4;           // rows per group
    constexpr int ROWS = RG * R;
    constexpr int H = HC / 64;
    __shared__ float W_lds[64 * HC];       // half of W (k-split) <= 32KB
    __shared__ float x_lds[ROWS * 128];

    const int tid = threadIdx.x;
    const int c = tid % HC;
    const int rgrp = tid / HC;
    const int head = c >> 6;
    const float asc = att_s[c];
    const float adc = att_d[c];

    const int ntiles = (N + ROWS - 1) / ROWS;
    for (int t = blockIdx.x; t < ntiles; t += gridDim.x) {
        const int row0 = t * ROWS;
        for (int i = tid; i < ROWS * 128; i += 256) {
            int row = row0 + (i >> 7);
            x_lds[i] = (row < N) ? x[(size_t)row * 128 + (i & 127)] : 0.f;
        }
        float acc[R];
#pragma unroll
        for (int r = 0; r < R; ++r) acc[r] = 0.f;

#pragma unroll
        for (int kh = 0; kh < 2; ++kh) {
            __syncthreads();   // covers x_lds load (kh=0) and prev compute (kh=1)
            for (int i = tid; i < 64 * HC; i += 256)
                W_lds[i] = W[(size_t)(kh * 64 + i / HC) * HC + (i % HC)];
            __syncthreads();
#pragma unroll
            for (int kk = 0; kk < 64; ++kk) {
                float w = W_lds[kk * HC + c];
#pragma unroll
                for (int r = 0; r < R; ++r)
                    acc[r] += x_lds[(rgrp * R + r) * 128 + kh * 64 + kk] * w;
            }
        }
#pragma unroll
        for (int r = 0; r < R; ++r) {
            int row = row0 + rgrp * R + r;   // uniform across the wave
            if (row < N) {
                h[(size_t)row * HC + c] = acc[r];
                float vs = acc[r] * asc;
                float vd = acc[r] * adc;
#pragma unroll
                for (int off = 32; off > 0; off >>= 1) {
                    vs += __shfl_down(vs, off);
                    vd += __shfl_down(vd, off);
                }
                if ((tid & 63) == 0) {
                    a_s[row * H + head] = vs;
                    a_d[row * H + head] = vd;
                }
            }
        }
        __syncthreads();
    }
}

// per-edge score = leaky_relu(a_s[src]+a_d[dst]); atomic segment max over dst
template<int H>
__global__ __launch_bounds__(256)
void edge_score(const int* __restrict__ ei, int E, int Etot,
                const float* __restrict__ a_s, const float* __restrict__ a_d,
                float* __restrict__ score, unsigned* __restrict__ m) {
    int i = blockIdx.x * 256 + threadIdx.x;
    int stride = gridDim.x * 256;
    for (int e = i; e < Etot; e += stride) {
        int src = (e < E) ? ei[e] : (e - E);
        int dst = (e < E) ? ei[E + e] : (e - E);
#pragma unroll
        for (int hh = 0; hh < H; ++hh) {
            float s = a_s[src * H + hh] + a_d[dst * H + hh];
            s = (s > 0.f) ? s : SLOPE * s;
            score[(size_t)e * H + hh] = s;
            atomicMax(&m[dst * H + hh], fmap(s));
        }
    }
}

// one wave per edge: ex = exp(score - m[dst]); denom[dst] += ex;
// acc[dst, :] += ex * h[src, :]
template<int H>
__global__ __launch_bounds__(256)
void edge_aggr(const int* __restrict__ ei, int E, int Etot,
               const float* __restrict__ score, const unsigned* __restrict__ m,
               float* __restrict__ denom, const float* __restrict__ h,
               float* __restrict__ acc) {
    int gw = (blockIdx.x * 256 + threadIdx.x) >> 6;
    int lane = threadIdx.x & 63;
    int nw = (gridDim.x * 256) >> 6;
    for (int e = gw; e < Etot; e += nw) {
        int src = (e < E) ? ei[e] : (e - E);
        int dst = (e < E) ? ei[E + e] : (e - E);
        if (H == 1) {
            float ex = __expf(score[e] - funmap(m[dst]));
            if (lane == 0) atomicAdd(&denom[dst], ex);
            float v = h[(size_t)src * 64 + lane];
            atomicAdd(&acc[(size_t)dst * 64 + lane], ex * v);
        } else {
            float ex0 = __expf(score[(size_t)e * 2]     - funmap(m[dst * 2]));
            float ex1 = __expf(score[(size_t)e * 2 + 1] - funmap(m[dst * 2 + 1]));
            if (lane == 0) atomicAdd(&denom[dst * 2], ex0);
            if (lane == 1) atomicAdd(&denom[dst * 2 + 1], ex1);
            float v0 = h[(size_t)src * 128 + lane];
            float v1 = h[(size_t)src * 128 + 64 + lane];
            atomicAdd(&acc[(size_t)dst * 128 + lane], ex0 * v0);
            atomicAdd(&acc[(size_t)dst * 128 + 64 + lane], ex1 * v1);
        }
    }
}

// out[n,j] = acc[n,j]/denom[n, j/64] + bias[j]; optional ELU
template<bool ELU, int HC>
__global__ __launch_bounds__(256)
void finalize(const float* __restrict__ acc, const float* __restrict__ denom,
              const float* __restrict__ bias, float* __restrict__ out, int N) {
    constexpr int H = HC / 64;
    int i = blockIdx.x * 256 + threadIdx.x;
    int stride = gridDim.x * 256;
    int total = N * HC;
    for (; i < total; i += stride) {
        int n = i / HC;
        int j = i % HC;
        float v = acc[i] / denom[n * H + (j >> 6)] + bias[j];
        if (ELU) v = (v > 0.f) ? v : expm1f(v);
        out[i] = v;
    }
}

extern "C" void kernel_launch(void* const* d_in, const int* in_sizes, int n_in,
                              void* d_out, int out_size, void* d_ws, size_t ws_size,
                              hipStream_t stream) {
    const float* x   = (const float*)d_in[0];
    const int*   ei  = (const int*)d_in[1];
    const float* W1  = (const float*)d_in[2];
    const float* as1 = (const float*)d_in[3];
    const float* ad1 = (const float*)d_in[4];
    const float* b1  = (const float*)d_in[5];
    const float* W2  = (const float*)d_in[6];
    const float* as2 = (const float*)d_in[7];
    const float* ad2 = (const float*)d_in[8];
    const float* b2  = (const float*)d_in[9];
    float* out = (float*)d_out;

    const int N = out_size / 64;          // 100000
    const int E = in_sizes[1] / 2;        // 1600000
    const int Etot = E + N;               // + self loops

    // workspace layout (floats):
    // [0, 128N)           h1 (layer-1 features; overwritten in-place by ELU output)
    // [128N, 256N)        accA: acc1; reused in layer 2 as h2 [0,64N) + acc2 [64N,128N)
    // [256N, 256N+2Etot)  per-edge scores (shared between layers)
    // then 12N of small per-node arrays
    float* ws    = (float*)d_ws;
    float* h1    = ws;
    float* accA  = ws + (size_t)N * 128;
    float* score = accA + (size_t)N * 128;
    float* small = score + (size_t)Etot * 2;
    float*    a_s1   = small;
    float*    a_d1   = small + 2 * (size_t)N;
    unsigned* m1     = (unsigned*)(small + 4 * (size_t)N);
    float*    denom1 = small + 6 * (size_t)N;
    float*    a_s2   = small + 8 * (size_t)N;
    float*    a_d2   = small + 9 * (size_t)N;
    unsigned* m2     = (unsigned*)(small + 10 * (size_t)N);
    float*    denom2 = small + 11 * (size_t)N;

    // ---- layer 1 ----
    hipMemsetAsync(m1, 0, (size_t)N * 16, stream);        // m1 (2N u32) + denom1 (2N f32)
    hipMemsetAsync(accA, 0, (size_t)N * 512, stream);     // acc1

    int tiles1 = (N + 7) / 8;
    gemm_att<128><<<dim3(imin(tiles1, 4096)), dim3(256), 0, stream>>>(
        x, W1, as1, ad1, h1, a_s1, a_d1, N);
    int eb = imin((Etot + 255) / 256, 8192);
    edge_score<2><<<dim3(eb), dim3(256), 0, stream>>>(ei, E, Etot, a_s1, a_d1, score, m1);
    edge_aggr<2><<<dim3(16384), dim3(256), 0, stream>>>(ei, E, Etot, score, m1, denom1, h1, accA);
    int fb1 = imin((N * 128 + 255) / 256, 8192);
    finalize<true, 128><<<dim3(fb1), dim3(256), 0, stream>>>(accA, denom1, b1, h1, N);

    // ---- layer 2 ----
    float* h2   = accA;                   // [N,64]
    float* acc2 = accA + (size_t)N * 64;  // [N,64]
    hipMemsetAsync(m2, 0, (size_t)N * 8, stream);         // m2 (N u32) + denom2 (N f32)
    hipMemsetAsync(acc2, 0, (size_t)N * 256, stream);

    int tiles2 = (N + 15) / 16;
    gemm_att<64><<<dim3(imin(tiles2, 4096)), dim3(256), 0, stream>>>(
        h1, W2, as2, ad2, h2, a_s2, a_d2, N);
    edge_score<1><<<dim3(eb), dim3(256), 0, stream>>>(ei, E, Etot, a_s2, a_d2, score, m2);
    edge_aggr<1><<<dim3(16384), dim3(256), 0, stream>>>(ei, E, Etot, score, m2, denom2, h2, acc2);
    int fb2 = imin((N * 64 + 255) / 256, 8192);
    finalize<false, 64><<<dim3(fb2), dim3(256), 0, stream>>>(acc2, denom2, b2, out, N);
}

// Round 2
// 1597.684 us; speedup vs baseline: 1.8144x; 1.8144x over previous
//
#include <hip/hip_runtime.h>
#include <hip/hip_bf16.h>
#include <math.h>

#define SLOPE 0.2f

static inline int imin(int a, int b) { return a < b ? a : b; }

// order-preserving float->uint map for atomicMax-based float max
__device__ __forceinline__ unsigned fmap(float f) {
    unsigned u = __float_as_uint(f);
    return (u & 0x80000000u) ? ~u : (u | 0x80000000u);
}
__device__ __forceinline__ float funmap(unsigned u) {
    unsigned v = (u & 0x80000000u) ? (u & 0x7FFFFFFFu) : ~u;
    return __uint_as_float(v);
}

// h = x @ W  (x:[N,128], W:[128,HC]), plus a_s[n,h]=sum_c h*att_s, a_d likewise.
// Register-lean LDS GEMM: W persistent in LDS, 4 rows x 4 cols per thread.
// HC=128: CG=32, RSLOTS=8, ROWS=32, x unpadded (2-way LDS alias is free),
//          LDS = 64K(W) + 16K(x) = 80K -> 2 blocks/CU.
// HC=64:  CG=16, RSLOTS=16, ROWS=64, x padded to stride 132 (4 rows/wave),
//          LDS = 32K + 33K = 65K -> 2 blocks/CU.
template<int HC>
__global__ __launch_bounds__(256, 2)
void gemm_att(const float* __restrict__ x, const float* __restrict__ W,
              const float* __restrict__ att_s, const float* __restrict__ att_d,
              float* __restrict__ h, float* __restrict__ a_s, float* __restrict__ a_d,
              int N) {
    constexpr int CG = HC / 4;          // float4 col-groups per row (32 or 16)
    constexpr int RSLOTS = 256 / CG;    // row slots (8 or 16)
    constexpr int R = 4;                // rows per slot
    constexpr int ROWS = RSLOTS * R;    // rows per block tile (32 or 64)
    constexpr int H = HC / 64;
    constexpr int XS = (HC == 128) ? 128 : 132;  // x_lds row stride (floats)

    __shared__ float4 W_lds[128 * CG];
    __shared__ float x_lds[ROWS * XS];

    const int tid = threadIdx.x;
    const int cg = tid % CG;
    const int rslot = tid / CG;

    // load full W once per block (row-major [128][HC] == flat float4s)
    for (int i = tid; i < 128 * CG; i += 256)
        W_lds[i] = ((const float4*)W)[i];

    const float4 asv = ((const float4*)att_s)[cg];
    const float4 adv = ((const float4*)att_d)[cg];

    const int ntiles = (N + ROWS - 1) / ROWS;
    for (int t = blockIdx.x; t < ntiles; t += gridDim.x) {
        const int row0 = t * ROWS;
        __syncthreads();   // prev-iter compute done (and, on iter 0, nothing)
        for (int i = tid; i < ROWS * 32; i += 256) {
            int r = i >> 5, k4 = i & 31;
            int row = row0 + r;
            float4 v = (row < N) ? ((const float4*)x)[(size_t)row * 32 + k4]
                                 : make_float4(0.f, 0.f, 0.f, 0.f);
            *(float4*)&x_lds[r * XS + k4 * 4] = v;
        }
        __syncthreads();   // x (and on iter 0, W) ready

        float4 acc[R];
#pragma unroll
        for (int r = 0; r < R; ++r) acc[r] = make_float4(0.f, 0.f, 0.f, 0.f);

#pragma unroll 4
        for (int k = 0; k < 128; ++k) {
            float4 w = W_lds[k * CG + cg];
#pragma unroll
            for (int r = 0; r < R; ++r) {
                float xv = x_lds[(rslot * R + r) * XS + k];
                acc[r].x = fmaf(xv, w.x, acc[r].x);
                acc[r].y = fmaf(xv, w.y, acc[r].y);
                acc[r].z = fmaf(xv, w.z, acc[r].z);
                acc[r].w = fmaf(xv, w.w, acc[r].w);
            }
        }

#pragma unroll
        for (int r = 0; r < R; ++r) {
            int row = row0 + rslot * R + r;   // uniform within 16-lane group
            if (row < N) {
                ((float4*)h)[(size_t)row * CG + cg] = acc[r];
                float vs = acc[r].x * asv.x + acc[r].y * asv.y
                         + acc[r].z * asv.z + acc[r].w * asv.w;
                float vd = acc[r].x * adv.x + acc[r].y * adv.y
                         + acc[r].z * adv.z + acc[r].w * adv.w;
#pragma unroll
                for (int off = 1; off < 16; off <<= 1) {
                    vs += __shfl_xor(vs, off);
                    vd += __shfl_xor(vd, off);
                }
                if ((tid & 15) == 0) {
                    int head = (H == 2) ? ((tid >> 4) & 1) : 0;
                    a_s[row * H + head] = vs;
                    a_d[row * H + head] = vd;
                }
            }
        }
    }
}

// per-edge score = leaky_relu(a_s[src]+a_d[dst]); atomic segment max over dst
template<int H>
__global__ __launch_bounds__(256)
void edge_score(const int* __restrict__ ei, int E, int Etot,
                const float* __restrict__ a_s, const float* __restrict__ a_d,
                float* __restrict__ score, unsigned* __restrict__ m) {
    int i = blockIdx.x * 256 + threadIdx.x;
    int stride = gridDim.x * 256;
    for (int e = i; e < Etot; e += stride) {
        int src = (e < E) ? ei[e] : (e - E);
        int dst = (e < E) ? ei[E + e] : (e - E);
#pragma unroll
        for (int hh = 0; hh < H; ++hh) {
            float s = a_s[src * H + hh] + a_d[dst * H + hh];
            s = (s > 0.f) ? s : SLOPE * s;
            score[(size_t)e * H + hh] = s;
            atomicMax(&m[dst * H + hh], fmap(s));
        }
    }
}

// one wave per edge: ex = exp(score - m[dst]); denom[dst] += ex;
// acc[dst, :] += ex * h[src, :]
template<int H>
__global__ __launch_bounds__(256)
void edge_aggr(const int* __restrict__ ei, int E, int Etot,
               const float* __restrict__ score, const unsigned* __restrict__ m,
               float* __restrict__ denom, const float* __restrict__ h,
               float* __restrict__ acc) {
    int gw = (blockIdx.x * 256 + threadIdx.x) >> 6;
    int lane = threadIdx.x & 63;
    int nw = (gridDim.x * 256) >> 6;
    for (int e = gw; e < Etot; e += nw) {
        int src = (e < E) ? ei[e] : (e - E);
        int dst = (e < E) ? ei[E + e] : (e - E);
        if (H == 1) {
            float ex = __expf(score[e] - funmap(m[dst]));
            if (lane == 0) atomicAdd(&denom[dst], ex);
            float v = h[(size_t)src * 64 + lane];
            atomicAdd(&acc[(size_t)dst * 64 + lane], ex * v);
        } else {
            float ex0 = __expf(score[(size_t)e * 2]     - funmap(m[dst * 2]));
            float ex1 = __expf(score[(size_t)e * 2 + 1] - funmap(m[dst * 2 + 1]));
            if (lane == 0) atomicAdd(&denom[dst * 2], ex0);
            if (lane == 1) atomicAdd(&denom[dst * 2 + 1], ex1);
            float v0 = h[(size_t)src * 128 + lane];
            float v1 = h[(size_t)src * 128 + 64 + lane];
            atomicAdd(&acc[(size_t)dst * 128 + lane], ex0 * v0);
            atomicAdd(&acc[(size_t)dst * 128 + 64 + lane], ex1 * v1);
        }
    }
}

// out[n,j] = acc[n,j]/denom[n, j/64] + bias[j]; optional ELU
template<bool ELU, int HC>
__global__ __launch_bounds__(256)
void finalize(const float* __restrict__ acc, const float* __restrict__ denom,
              const float* __restrict__ bias, float* __restrict__ out, int N) {
    constexpr int H = HC / 64;
    int i = blockIdx.x * 256 + threadIdx.x;
    int stride = gridDim.x * 256;
    int total = N * HC;
    for (; i < total; i += stride) {
        int n = i / HC;
        int j = i % HC;
        float v = acc[i] / denom[n * H + (j >> 6)] + bias[j];
        if (ELU) v = (v > 0.f) ? v : expm1f(v);
        out[i] = v;
    }
}

extern "C" void kernel_launch(void* const* d_in, const int* in_sizes, int n_in,
                              void* d_out, int out_size, void* d_ws, size_t ws_size,
                              hipStream_t stream) {
    const float* x   = (const float*)d_in[0];
    const int*   ei  = (const int*)d_in[1];
    const float* W1  = (const float*)d_in[2];
    const float* as1 = (const float*)d_in[3];
    const float* ad1 = (const float*)d_in[4];
    const float* b1  = (const float*)d_in[5];
    const float* W2  = (const float*)d_in[6];
    const float* as2 = (const float*)d_in[7];
    const float* ad2 = (const float*)d_in[8];
    const float* b2  = (const float*)d_in[9];
    float* out = (float*)d_out;

    const int N = out_size / 64;          // 100000
    const int E = in_sizes[1] / 2;        // 1600000
    const int Etot = E + N;               // + self loops

    // workspace layout (floats):
    // [0, 128N)           h1 (layer-1 features; overwritten in-place by ELU output)
    // [128N, 256N)        accA: acc1; reused in layer 2 as h2 [0,64N) + acc2 [64N,128N)
    // [256N, 256N+2Etot)  per-edge scores (shared between layers)
    // then 12N of small per-node arrays
    float* ws    = (float*)d_ws;
    float* h1    = ws;
    float* accA  = ws + (size_t)N * 128;
    float* score = accA + (size_t)N * 128;
    float* small = score + (size_t)Etot * 2;
    float*    a_s1   = small;
    float*    a_d1   = small + 2 * (size_t)N;
    unsigned* m1     = (unsigned*)(small + 4 * (size_t)N);
    float*    denom1 = small + 6 * (size_t)N;
    float*    a_s2   = small + 8 * (size_t)N;
    float*    a_d2   = small + 9 * (size_t)N;
    unsigned* m2     = (unsigned*)(small + 10 * (size_t)N);
    float*    denom2 = small + 11 * (size_t)N;

    // ---- layer 1 ----
    hipMemsetAsync(m1, 0, (size_t)N * 16, stream);        // m1 (2N u32) + denom1 (2N f32)
    hipMemsetAsync(accA, 0, (size_t)N * 512, stream);     // acc1

    gemm_att<128><<<dim3(1024), dim3(256), 0, stream>>>(
        x, W1, as1, ad1, h1, a_s1, a_d1, N);
    int eb = imin((Etot + 255) / 256, 8192);
    edge_score<2><<<dim3(eb), dim3(256), 0, stream>>>(ei, E, Etot, a_s1, a_d1, score, m1);
    edge_aggr<2><<<dim3(16384), dim3(256), 0, stream>>>(ei, E, Etot, score, m1, denom1, h1, accA);
    int fb1 = imin((N * 128 + 255) / 256, 8192);
    finalize<true, 128><<<dim3(fb1), dim3(256), 0, stream>>>(accA, denom1, b1, h1, N);

    // ---- layer 2 ----
    float* h2   = accA;                   // [N,64]
    float* acc2 = accA + (size_t)N * 64;  // [N,64]
    hipMemsetAsync(m2, 0, (size_t)N * 8, stream);         // m2 (N u32) + denom2 (N f32)
    hipMemsetAsync(acc2, 0, (size_t)N * 256, stream);

    gemm_att<64><<<dim3(1024), dim3(256), 0, stream>>>(
        h1, W2, as2, ad2, h2, a_s2, a_d2, N);
    edge_score<1><<<dim3(eb), dim3(256), 0, stream>>>(ei, E, Etot, a_s2, a_d2, score, m2);
    edge_aggr<1><<<dim3(16384), dim3(256), 0, stream>>>(ei, E, Etot, score, m2, denom2, h2, acc2);
    int fb2 = imin((N * 64 + 255) / 256, 8192);
    finalize<false, 64><<<dim3(fb2), dim3(256), 0, stream>>>(acc2, denom2, b2, out, N);
}

// Round 3
// 586.909 us; speedup vs baseline: 4.9391x; 2.7222x over previous
//
#include <hip/hip_runtime.h>
#include <hip/hip_bf16.h>
#include <math.h>

#define SLOPE 0.2f

static inline int imin(int a, int b) { return a < b ? a : b; }

// ---------------- GEMM + attention dots (unchanged from round 2) ----------------
template<int HC>
__global__ __launch_bounds__(256, 2)
void gemm_att(const float* __restrict__ x, const float* __restrict__ W,
              const float* __restrict__ att_s, const float* __restrict__ att_d,
              float* __restrict__ h, float* __restrict__ a_s, float* __restrict__ a_d,
              int N) {
    constexpr int CG = HC / 4;
    constexpr int RSLOTS = 256 / CG;
    constexpr int R = 4;
    constexpr int ROWS = RSLOTS * R;
    constexpr int H = HC / 64;
    constexpr int XS = (HC == 128) ? 128 : 132;

    __shared__ float4 W_lds[128 * CG];
    __shared__ float x_lds[ROWS * XS];

    const int tid = threadIdx.x;
    const int cg = tid % CG;
    const int rslot = tid / CG;

    for (int i = tid; i < 128 * CG; i += 256)
        W_lds[i] = ((const float4*)W)[i];

    const float4 asv = ((const float4*)att_s)[cg];
    const float4 adv = ((const float4*)att_d)[cg];

    const int ntiles = (N + ROWS - 1) / ROWS;
    for (int t = blockIdx.x; t < ntiles; t += gridDim.x) {
        const int row0 = t * ROWS;
        __syncthreads();
        for (int i = tid; i < ROWS * 32; i += 256) {
            int r = i >> 5, k4 = i & 31;
            int row = row0 + r;
            float4 v = (row < N) ? ((const float4*)x)[(size_t)row * 32 + k4]
                                 : make_float4(0.f, 0.f, 0.f, 0.f);
            *(float4*)&x_lds[r * XS + k4 * 4] = v;
        }
        __syncthreads();

        float4 acc[R];
#pragma unroll
        for (int r = 0; r < R; ++r) acc[r] = make_float4(0.f, 0.f, 0.f, 0.f);

#pragma unroll 4
        for (int k = 0; k < 128; ++k) {
            float4 w = W_lds[k * CG + cg];
#pragma unroll
            for (int r = 0; r < R; ++r) {
                float xv = x_lds[(rslot * R + r) * XS + k];
                acc[r].x = fmaf(xv, w.x, acc[r].x);
                acc[r].y = fmaf(xv, w.y, acc[r].y);
                acc[r].z = fmaf(xv, w.z, acc[r].z);
                acc[r].w = fmaf(xv, w.w, acc[r].w);
            }
        }

#pragma unroll
        for (int r = 0; r < R; ++r) {
            int row = row0 + rslot * R + r;
            if (row < N) {
                ((float4*)h)[(size_t)row * CG + cg] = acc[r];
                float vs = acc[r].x * asv.x + acc[r].y * asv.y
                         + acc[r].z * asv.z + acc[r].w * asv.w;
                float vd = acc[r].x * adv.x + acc[r].y * adv.y
                         + acc[r].z * adv.z + acc[r].w * adv.w;
#pragma unroll
                for (int off = 1; off < 16; off <<= 1) {
                    vs += __shfl_xor(vs, off);
                    vd += __shfl_xor(vd, off);
                }
                if ((tid & 15) == 0) {
                    int head = (H == 2) ? ((tid >> 4) & 1) : 0;
                    a_s[row * H + head] = vs;
                    a_d[row * H + head] = vd;
                }
            }
        }
    }
}

// ---------------- CSR build (dst-sorted), once per call ----------------
__global__ __launch_bounds__(256)
void histo_k(const int* __restrict__ ei, int E, int Etot, int* __restrict__ cnt) {
    int i = blockIdx.x * 256 + threadIdx.x, st = gridDim.x * 256;
    for (int e = i; e < Etot; e += st) {
        int dst = (e < E) ? ei[E + e] : (e - E);
        atomicAdd(&cnt[dst], 1);
    }
}

// per-256-block exclusive scan; block sums out. excl written into rowptr.
__global__ __launch_bounds__(256)
void scan1_k(const int* __restrict__ cnt, int* __restrict__ excl,
             int* __restrict__ bsum, int N) {
    __shared__ int sm[256];
    int t = threadIdx.x, g = blockIdx.x * 256 + t;
    int v = (g < N) ? cnt[g] : 0;
    sm[t] = v; __syncthreads();
    for (int off = 1; off < 256; off <<= 1) {
        int u = (t >= off) ? sm[t - off] : 0;
        __syncthreads();
        sm[t] += u;
        __syncthreads();
    }
    if (g < N) excl[g] = sm[t] - v;
    if (t == 255) bsum[blockIdx.x] = sm[255];
}

// single block: exclusive scan of up to 512 block sums
__global__ __launch_bounds__(512)
void scan2_k(int* __restrict__ bsum, int nb) {
    __shared__ int sm[512];
    int t = threadIdx.x;
    int v = (t < nb) ? bsum[t] : 0;
    sm[t] = v; __syncthreads();
    for (int off = 1; off < 512; off <<= 1) {
        int u = (t >= off) ? sm[t - off] : 0;
        __syncthreads();
        sm[t] += u;
        __syncthreads();
    }
    if (t < nb) bsum[t] = sm[t] - v;
}

__global__ __launch_bounds__(256)
void scan3_k(int* __restrict__ rowptr, const int* __restrict__ bsum,
             int* __restrict__ next, int N, int Etot) {
    int g = blockIdx.x * 256 + threadIdx.x;
    if (g < N) {
        int v = rowptr[g] + bsum[g >> 8];
        rowptr[g] = v;
        next[g] = v;
    }
    if (g == 0) rowptr[N] = Etot;
}

__global__ __launch_bounds__(256)
void scatter_k(const int* __restrict__ ei, int E, int Etot,
               int* __restrict__ next, int* __restrict__ colsrc) {
    int i = blockIdx.x * 256 + threadIdx.x, st = gridDim.x * 256;
    for (int e = i; e < Etot; e += st) {
        int src = (e < E) ? ei[e] : (e - E);
        int dst = (e < E) ? ei[E + e] : (e - E);
        int p = atomicAdd(&next[dst], 1);
        colsrc[p] = src;
    }
}

// ---------------- fused per-node aggregation ----------------
// one wave per dst node: pass 1 = score max (registers), pass 2 = exp-weighted
// gather-accumulate of h[src], epilogue = normalize + bias (+ELU).
// H==2: lane l holds channels (2l,2l+1): l<32 -> head0, l>=32 -> head1.
template<int H, bool ELU>
__global__ __launch_bounds__(256)
void node_aggr(const int* __restrict__ rowptr, const int* __restrict__ colsrc,
               const float* __restrict__ a_s, const float* __restrict__ a_d,
               const float* __restrict__ h, const float* __restrict__ bias,
               float* __restrict__ out, int N) {
    int gw = (blockIdx.x * 256 + threadIdx.x) >> 6;
    int lane = threadIdx.x & 63;
    int nw = (gridDim.x * 256) >> 6;

    for (int n = gw; n < N; n += nw) {
        const int b = rowptr[n], deg = rowptr[n + 1] - b;

        if (H == 2) {
            const float2* as2 = (const float2*)a_s;
            const float2 adn = ((const float2*)a_d)[n];
            // pass 1: per-head max
            float m0 = -INFINITY, m1 = -INFINITY;
            for (int i = lane; i < deg; i += 64) {
                int src = colsrc[b + i];
                float2 as = as2[src];
                float s0 = as.x + adn.x; s0 = s0 > 0.f ? s0 : SLOPE * s0;
                float s1 = as.y + adn.y; s1 = s1 > 0.f ? s1 : SLOPE * s1;
                m0 = fmaxf(m0, s0); m1 = fmaxf(m1, s1);
            }
#pragma unroll
            for (int off = 32; off; off >>= 1) {
                m0 = fmaxf(m0, __shfl_xor(m0, off));
                m1 = fmaxf(m1, __shfl_xor(m1, off));
            }
            const float msel = (lane < 32) ? m0 : m1;
            // pass 2
            float accx = 0.f, accy = 0.f, den = 0.f;
            for (int c = 0; c < deg; c += 64) {
                int ii = c + lane;
                int src_r = 0; float s0_r = 0.f, s1_r = 0.f;
                if (ii < deg) {
                    src_r = colsrc[b + ii];
                    float2 as = as2[src_r];
                    s0_r = as.x + adn.x; s0_r = s0_r > 0.f ? s0_r : SLOPE * s0_r;
                    s1_r = as.y + adn.y; s1_r = s1_r > 0.f ? s1_r : SLOPE * s1_r;
                }
                int lim = (deg - c < 64) ? (deg - c) : 64;
                for (int i = 0; i < lim; ++i) {
                    int src = __shfl(src_r, i);
                    float s0b = __shfl(s0_r, i);
                    float s1b = __shfl(s1_r, i);
                    float w = __expf(((lane < 32) ? s0b : s1b) - msel);
                    den += w;
                    float2 hv = ((const float2*)h)[(size_t)src * 64 + lane];
                    accx = fmaf(w, hv.x, accx);
                    accy = fmaf(w, hv.y, accy);
                }
            }
            float2 bv = ((const float2*)bias)[lane];
            float vx = accx / den + bv.x;
            float vy = accy / den + bv.y;
            if (ELU) {
                vx = vx > 0.f ? vx : expm1f(vx);
                vy = vy > 0.f ? vy : expm1f(vy);
            }
            ((float2*)out)[(size_t)n * 64 + lane] = make_float2(vx, vy);
        } else {
            const float adn = a_d[n];
            float m = -INFINITY;
            for (int i = lane; i < deg; i += 64) {
                float s = a_s[colsrc[b + i]] + adn;
                s = s > 0.f ? s : SLOPE * s;
                m = fmaxf(m, s);
            }
#pragma unroll
            for (int off = 32; off; off >>= 1) m = fmaxf(m, __shfl_xor(m, off));
            float acc = 0.f, den = 0.f;
            for (int c = 0; c < deg; c += 64) {
                int ii = c + lane;
                int src_r = 0; float s_r = 0.f;
                if (ii < deg) {
                    src_r = colsrc[b + ii];
                    s_r = a_s[src_r] + adn;
                    s_r = s_r > 0.f ? s_r : SLOPE * s_r;
                }
                int lim = (deg - c < 64) ? (deg - c) : 64;
                for (int i = 0; i < lim; ++i) {
                    int src = __shfl(src_r, i);
                    float w = __expf(__shfl(s_r, i) - m);
                    den += w;
                    acc = fmaf(w, h[(size_t)src * 64 + lane], acc);
                }
            }
            float v = acc / den + bias[lane];
            if (ELU) v = v > 0.f ? v : expm1f(v);
            out[(size_t)n * 64 + lane] = v;
        }
    }
}

extern "C" void kernel_launch(void* const* d_in, const int* in_sizes, int n_in,
                              void* d_out, int out_size, void* d_ws, size_t ws_size,
                              hipStream_t stream) {
    const float* x   = (const float*)d_in[0];
    const int*   ei  = (const int*)d_in[1];
    const float* W1  = (const float*)d_in[2];
    const float* as1 = (const float*)d_in[3];
    const float* ad1 = (const float*)d_in[4];
    const float* b1  = (const float*)d_in[5];
    const float* W2  = (const float*)d_in[6];
    const float* as2 = (const float*)d_in[7];
    const float* ad2 = (const float*)d_in[8];
    const float* b2  = (const float*)d_in[9];
    float* out = (float*)d_out;

    const int N = out_size / 64;          // 100000
    const int E = in_sizes[1] / 2;        // 1600000
    const int Etot = E + N;               // + self loops

    // workspace layout:
    // floats: h1 [128N] | h1e [128N] | a_s1 [2N] | a_d1 [2N] | a_s2 [N] | a_d2 [N]
    // ints:   rowptr [N+1] | next [N] | bsum [512] | colsrc [Etot]
    float* ws   = (float*)d_ws;
    float* h1   = ws;                          // layer-2 h2 aliases h1 (dead by then)
    float* h1e  = ws + (size_t)N * 128;
    float* a_s1 = h1e + (size_t)N * 128;
    float* a_d1 = a_s1 + (size_t)N * 2;
    float* a_s2 = a_d1 + (size_t)N * 2;
    float* a_d2 = a_s2 + (size_t)N;
    int* rowptr = (int*)(a_d2 + (size_t)N);
    int* next   = rowptr + (N + 1);
    int* bsum   = next + N;
    int* colsrc = bsum + 512;

    // ---- CSR build (shared by both layers) ----
    hipMemsetAsync(next, 0, (size_t)N * 4, stream);
    int eb = imin((Etot + 255) / 256, 4096);
    int nb1 = (N + 255) / 256;                  // 391 (<=512 for scan2)
    histo_k<<<dim3(eb), dim3(256), 0, stream>>>(ei, E, Etot, next);
    scan1_k<<<dim3(nb1), dim3(256), 0, stream>>>(next, rowptr, bsum, N);
    scan2_k<<<dim3(1), dim3(512), 0, stream>>>(bsum, nb1);
    scan3_k<<<dim3(nb1), dim3(256), 0, stream>>>(rowptr, bsum, next, N, Etot);
    scatter_k<<<dim3(eb), dim3(256), 0, stream>>>(ei, E, Etot, next, colsrc);

    int ab = imin((N + 3) / 4, 25000);

    // ---- layer 1 ----
    gemm_att<128><<<dim3(1024), dim3(256), 0, stream>>>(
        x, W1, as1, ad1, h1, a_s1, a_d1, N);
    node_aggr<2, true><<<dim3(ab), dim3(256), 0, stream>>>(
        rowptr, colsrc, a_s1, a_d1, h1, b1, h1e, N);

    // ---- layer 2 ----
    float* h2 = h1;   // h1 dead after node_aggr<2>
    gemm_att<64><<<dim3(1024), dim3(256), 0, stream>>>(
        h1e, W2, as2, ad2, h2, a_s2, a_d2, N);
    node_aggr<1, false><<<dim3(ab), dim3(256), 0, stream>>>(
        rowptr, colsrc, a_s2, a_d2, h2, b2, out, N);
}

// Round 4
// 571.502 us; speedup vs baseline: 5.0723x; 1.0270x over previous
//
#include <hip/hip_runtime.h>
#include <hip/hip_bf16.h>
#include <math.h>

#define SLOPE 0.2f

static inline int imin(int a, int b) { return a < b ? a : b; }

// ---------------- GEMM + attention dots ----------------
template<int HC>
__global__ __launch_bounds__(256, 2)
void gemm_att(const float* __restrict__ x, const float* __restrict__ W,
              const float* __restrict__ att_s, const float* __restrict__ att_d,
              float* __restrict__ h, float* __restrict__ a_s, float* __restrict__ a_d,
              int N) {
    constexpr int CG = HC / 4;
    constexpr int RSLOTS = 256 / CG;
    constexpr int R = 4;
    constexpr int ROWS = RSLOTS * R;
    constexpr int H = HC / 64;
    constexpr int XS = (HC == 128) ? 128 : 132;

    __shared__ float4 W_lds[128 * CG];
    __shared__ float x_lds[ROWS * XS];

    const int tid = threadIdx.x;
    const int cg = tid % CG;
    const int rslot = tid / CG;

    for (int i = tid; i < 128 * CG; i += 256)
        W_lds[i] = ((const float4*)W)[i];

    const float4 asv = ((const float4*)att_s)[cg];
    const float4 adv = ((const float4*)att_d)[cg];

    const int ntiles = (N + ROWS - 1) / ROWS;
    for (int t = blockIdx.x; t < ntiles; t += gridDim.x) {
        const int row0 = t * ROWS;
        __syncthreads();
        for (int i = tid; i < ROWS * 32; i += 256) {
            int r = i >> 5, k4 = i & 31;
            int row = row0 + r;
            float4 v = (row < N) ? ((const float4*)x)[(size_t)row * 32 + k4]
                                 : make_float4(0.f, 0.f, 0.f, 0.f);
            *(float4*)&x_lds[r * XS + k4 * 4] = v;
        }
        __syncthreads();

        float4 acc[R];
#pragma unroll
        for (int r = 0; r < R; ++r) acc[r] = make_float4(0.f, 0.f, 0.f, 0.f);

#pragma unroll 4
        for (int k = 0; k < 128; ++k) {
            float4 w = W_lds[k * CG + cg];
#pragma unroll
            for (int r = 0; r < R; ++r) {
                float xv = x_lds[(rslot * R + r) * XS + k];
                acc[r].x = fmaf(xv, w.x, acc[r].x);
                acc[r].y = fmaf(xv, w.y, acc[r].y);
                acc[r].z = fmaf(xv, w.z, acc[r].z);
                acc[r].w = fmaf(xv, w.w, acc[r].w);
            }
        }

#pragma unroll
        for (int r = 0; r < R; ++r) {
            int row = row0 + rslot * R + r;
            if (row < N) {
                ((float4*)h)[(size_t)row * CG + cg] = acc[r];
                float vs = acc[r].x * asv.x + acc[r].y * asv.y
                         + acc[r].z * asv.z + acc[r].w * asv.w;
                float vd = acc[r].x * adv.x + acc[r].y * adv.y
                         + acc[r].z * adv.z + acc[r].w * adv.w;
#pragma unroll
                for (int off = 1; off < 16; off <<= 1) {
                    vs += __shfl_xor(vs, off);
                    vd += __shfl_xor(vd, off);
                }
                if ((tid & 15) == 0) {
                    int head = (H == 2) ? ((tid >> 4) & 1) : 0;
                    a_s[row * H + head] = vs;
                    a_d[row * H + head] = vd;
                }
            }
        }
    }
}

// ---------------- CSR build (dst-sorted), once per call ----------------
__global__ __launch_bounds__(256)
void histo_k(const int* __restrict__ ei, int E, int Etot, int* __restrict__ cnt) {
    int i = blockIdx.x * 256 + threadIdx.x, st = gridDim.x * 256;
    for (int e = i; e < Etot; e += st) {
        int dst = (e < E) ? ei[E + e] : (e - E);
        atomicAdd(&cnt[dst], 1);
    }
}

__global__ __launch_bounds__(256)
void scan1_k(const int* __restrict__ cnt, int* __restrict__ excl,
             int* __restrict__ bsum, int N) {
    __shared__ int sm[256];
    int t = threadIdx.x, g = blockIdx.x * 256 + t;
    int v = (g < N) ? cnt[g] : 0;
    sm[t] = v; __syncthreads();
    for (int off = 1; off < 256; off <<= 1) {
        int u = (t >= off) ? sm[t - off] : 0;
        __syncthreads();
        sm[t] += u;
        __syncthreads();
    }
    if (g < N) excl[g] = sm[t] - v;
    if (t == 255) bsum[blockIdx.x] = sm[255];
}

__global__ __launch_bounds__(512)
void scan2_k(int* __restrict__ bsum, int nb) {
    __shared__ int sm[512];
    int t = threadIdx.x;
    int v = (t < nb) ? bsum[t] : 0;
    sm[t] = v; __syncthreads();
    for (int off = 1; off < 512; off <<= 1) {
        int u = (t >= off) ? sm[t - off] : 0;
        __syncthreads();
        sm[t] += u;
        __syncthreads();
    }
    if (t < nb) bsum[t] = sm[t] - v;
}

__global__ __launch_bounds__(256)
void scan3_k(int* __restrict__ rowptr, const int* __restrict__ bsum,
             int* __restrict__ next, int N, int Etot) {
    int g = blockIdx.x * 256 + threadIdx.x;
    if (g < N) {
        int v = rowptr[g] + bsum[g >> 8];
        rowptr[g] = v;
        next[g] = v;
    }
    if (g == 0) rowptr[N] = Etot;
}

__global__ __launch_bounds__(256)
void scatter_k(const int* __restrict__ ei, int E, int Etot,
               int* __restrict__ next, int* __restrict__ colsrc) {
    int i = blockIdx.x * 256 + threadIdx.x, st = gridDim.x * 256;
    for (int e = i; e < Etot; e += st) {
        int src = (e < E) ? ei[e] : (e - E);
        int dst = (e < E) ? ei[E + e] : (e - E);
        int p = atomicAdd(&next[dst], 1);
        colsrc[p] = src;
    }
}

// ---------------- fused per-node aggregation, single-pass online softmax ----
// one wave per dst node. Per 64-edge chunk: lane i loads edge (c+i)'s src and
// computes its score + weight w=exp(s-m) ONCE; inner loop shfl-broadcasts
// (src, w) and every lane accumulates its 2 channels. Rescale on new max
// (deg ~ Poisson(17): multi-chunk path is ~never taken).
template<int H, bool ELU>
__global__ __launch_bounds__(256)
void node_aggr(const int* __restrict__ rowptr, const int* __restrict__ colsrc,
               const float* __restrict__ a_s, const float* __restrict__ a_d,
               const float* __restrict__ h, const float* __restrict__ bias,
               float* __restrict__ out, int N) {
    int gw = (blockIdx.x * 256 + threadIdx.x) >> 6;
    int lane = threadIdx.x & 63;
    int nw = (gridDim.x * 256) >> 6;

    for (int n = gw; n < N; n += nw) {
        const int b = rowptr[n], deg = rowptr[n + 1] - b;

        if (H == 2) {
            const float2 adn = ((const float2*)a_d)[n];
            float m0 = -INFINITY, m1 = -INFINITY;
            float accx = 0.f, accy = 0.f, den = 0.f;
            for (int c = 0; c < deg; c += 64) {
                int ii = c + lane;
                int src_r = 0;
                float s0_r = -INFINITY, s1_r = -INFINITY;
                if (ii < deg) {
                    src_r = colsrc[b + ii];
                    float2 as = ((const float2*)a_s)[src_r];
                    s0_r = as.x + adn.x; s0_r = s0_r > 0.f ? s0_r : SLOPE * s0_r;
                    s1_r = as.y + adn.y; s1_r = s1_r > 0.f ? s1_r : SLOPE * s1_r;
                }
                float c0 = s0_r, c1 = s1_r;
#pragma unroll
                for (int off = 32; off; off >>= 1) {
                    c0 = fmaxf(c0, __shfl_xor(c0, off));
                    c1 = fmaxf(c1, __shfl_xor(c1, off));
                }
                float nm0 = fmaxf(m0, c0), nm1 = fmaxf(m1, c1);
                if (c > 0) {   // rescale previous chunks (rare)
                    float sc = (lane < 32) ? __expf(m0 - nm0) : __expf(m1 - nm1);
                    accx *= sc; accy *= sc; den *= sc;
                }
                m0 = nm0; m1 = nm1;
                float w0_r = __expf(s0_r - m0);   // 0 for inactive lanes
                float w1_r = __expf(s1_r - m1);
                int lim = (deg - c < 64) ? (deg - c) : 64;
#pragma unroll 2
                for (int i = 0; i < lim; ++i) {
                    int src = __shfl(src_r, i);
                    float w0b = __shfl(w0_r, i);
                    float w1b = __shfl(w1_r, i);
                    float w = (lane < 32) ? w0b : w1b;
                    den += w;
                    float2 hv = ((const float2*)h)[(size_t)src * 64 + lane];
                    accx = fmaf(w, hv.x, accx);
                    accy = fmaf(w, hv.y, accy);
                }
            }
            float2 bv = ((const float2*)bias)[lane];
            float vx = accx / den + bv.x;
            float vy = accy / den + bv.y;
            if (ELU) {
                vx = vx > 0.f ? vx : expm1f(vx);
                vy = vy > 0.f ? vy : expm1f(vy);
            }
            ((float2*)out)[(size_t)n * 64 + lane] = make_float2(vx, vy);
        } else {
            const float adn = a_d[n];
            float m = -INFINITY, acc = 0.f, den = 0.f;
            for (int c = 0; c < deg; c += 64) {
                int ii = c + lane;
                int src_r = 0;
                float s_r = -INFINITY;
                if (ii < deg) {
                    src_r = colsrc[b + ii];
                    s_r = a_s[src_r] + adn;
                    s_r = s_r > 0.f ? s_r : SLOPE * s_r;
                }
                float cm = s_r;
#pragma unroll
                for (int off = 32; off; off >>= 1) cm = fmaxf(cm, __shfl_xor(cm, off));
                float nm = fmaxf(m, cm);
                if (c > 0) {
                    float sc = __expf(m - nm);
                    acc *= sc; den *= sc;
                }
                m = nm;
                float w_r = __expf(s_r - m);
                int lim = (deg - c < 64) ? (deg - c) : 64;
#pragma unroll 2
                for (int i = 0; i < lim; ++i) {
                    int src = __shfl(src_r, i);
                    float w = __shfl(w_r, i);
                    den += w;
                    acc = fmaf(w, h[(size_t)src * 64 + lane], acc);
                }
            }
            float v = acc / den + bias[lane];
            if (ELU) v = v > 0.f ? v : expm1f(v);
            out[(size_t)n * 64 + lane] = v;
        }
    }
}

extern "C" void kernel_launch(void* const* d_in, const int* in_sizes, int n_in,
                              void* d_out, int out_size, void* d_ws, size_t ws_size,
                              hipStream_t stream) {
    const float* x   = (const float*)d_in[0];
    const int*   ei  = (const int*)d_in[1];
    const float* W1  = (const float*)d_in[2];
    const float* as1 = (const float*)d_in[3];
    const float* ad1 = (const float*)d_in[4];
    const float* b1  = (const float*)d_in[5];
    const float* W2  = (const float*)d_in[6];
    const float* as2 = (const float*)d_in[7];
    const float* ad2 = (const float*)d_in[8];
    const float* b2  = (const float*)d_in[9];
    float* out = (float*)d_out;

    const int N = out_size / 64;          // 100000
    const int E = in_sizes[1] / 2;        // 1600000
    const int Etot = E + N;               // + self loops

    float* ws   = (float*)d_ws;
    float* h1   = ws;                          // layer-2 h2 aliases h1 (dead by then)
    float* h1e  = ws + (size_t)N * 128;
    float* a_s1 = h1e + (size_t)N * 128;
    float* a_d1 = a_s1 + (size_t)N * 2;
    float* a_s2 = a_d1 + (size_t)N * 2;
    float* a_d2 = a_s2 + (size_t)N;
    int* rowptr = (int*)(a_d2 + (size_t)N);
    int* next   = rowptr + (N + 1);
    int* bsum   = next + N;
    int* colsrc = bsum + 512;

    // ---- CSR build (shared by both layers) ----
    hipMemsetAsync(next, 0, (size_t)N * 4, stream);
    int eb = imin((Etot + 255) / 256, 4096);
    int nb1 = (N + 255) / 256;                  // 391 (<=512 for scan2)
    histo_k<<<dim3(eb), dim3(256), 0, stream>>>(ei, E, Etot, next);
    scan1_k<<<dim3(nb1), dim3(256), 0, stream>>>(next, rowptr, bsum, N);
    scan2_k<<<dim3(1), dim3(512), 0, stream>>>(bsum, nb1);
    scan3_k<<<dim3(nb1), dim3(256), 0, stream>>>(rowptr, bsum, next, N, Etot);
    scatter_k<<<dim3(eb), dim3(256), 0, stream>>>(ei, E, Etot, next, colsrc);

    int ab = imin((N + 3) / 4, 25000);

    // ---- layer 1 ----
    gemm_att<128><<<dim3(1024), dim3(256), 0, stream>>>(
        x, W1, as1, ad1, h1, a_s1, a_d1, N);
    node_aggr<2, true><<<dim3(ab), dim3(256), 0, stream>>>(
        rowptr, colsrc, a_s1, a_d1, h1, b1, h1e, N);

    // ---- layer 2 ----
    float* h2 = h1;   // h1 dead after node_aggr<2>
    gemm_att<64><<<dim3(1024), dim3(256), 0, stream>>>(
        h1e, W2, as2, ad2, h2, a_s2, a_d2, N);
    node_aggr<1, false><<<dim3(ab), dim3(256), 0, stream>>>(
        rowptr, colsrc, a_s2, a_d2, h2, b2, out, N);
}